// Round 2
// baseline (622.113 us; speedup 1.0000x reference)
//
#include <hip/hip_runtime.h>
#include <stdint.h>
#include <limits.h>

// ---------------------------------------------------------------------------
// GeToInformedNeighborSampler — deterministic, graph-replay-safe version.
//
// Semantics (JAX reference):
//   logp[j] = log(adj_probs[geto[ids[j/D]*D + j%D]]),  j in [0, NC), NC = B*D
//   idx[s]  = argmax_j ( gumbel[s*NC+j] + logp[j] ),   s in [0, S=D)
//   r[s]    = clip(idx[s], 0, D-1)
//   out0[b,s] = adj[ids[b]*D + r[s]],  out1[b,s] = geto[ids[b]*D + r[s]]
//
// RNG: threefry2x32 key (0,42), classic JAX split form over n = S*NC draws:
//   half = n/2; for i < half:  bits_i = o0(TF(key, (i, i+half)))
//               for i >= half: bits_i = o1(TF(key, (i-half, i)))
//   u = max(tiny, bits2float01(bits)); g = -log(-log(u))
//
// Exact pruning: lp < 0 always (probs < 1), so any j that can beat running
// max m satisfies g_j > m  =>  u_j > exp(-exp(-m)). With conservative slack,
// accept iff (bits>>9) >= k(m). Fast path = threefry + 1 uint compare.
//
// XCD-coherence discipline (G16): every cross-kernel ws handoff uses
// AGENT-scope atomics (coherence-point accesses) so graph replay cannot see
// stale per-XCD L2 lines. Inputs are read-only; d_out written by one kernel.
// ---------------------------------------------------------------------------

__device__ __forceinline__ uint32_t rotl32(uint32_t x, int n) {
  return (x << n) | (x >> (32 - n));
}

// Threefry-2x32-20 with key (0, 42) == jax.random.key(42)
__device__ __forceinline__ void tf2x32_k42(uint32_t c0, uint32_t c1,
                                           uint32_t& o0, uint32_t& o1) {
  const uint32_t K0 = 0u, K1 = 42u;
  const uint32_t K2 = 0x1BD11BDAu ^ K0 ^ K1;
  uint32_t x0 = c0 + K0, x1 = c1 + K1;
#define TFR(r) x0 += x1; x1 = rotl32(x1, (r)); x1 ^= x0;
  TFR(13) TFR(15) TFR(26) TFR(6)
  x0 += K1; x1 += K2 + 1u;
  TFR(17) TFR(29) TFR(16) TFR(24)
  x0 += K2; x1 += K0 + 2u;
  TFR(13) TFR(15) TFR(26) TFR(6)
  x0 += K0; x1 += K1 + 3u;
  TFR(17) TFR(29) TFR(16) TFR(24)
  x0 += K1; x1 += K2 + 4u;
  TFR(13) TFR(15) TFR(26) TFR(6)
  x0 += K2; x1 += K0 + 5u;
#undef TFR
  o0 = x0; o1 = x1;
}

// Device-scope (agent) coherence-point load/store — safe across kernels/XCDs.
__device__ __forceinline__ uint32_t ld_dev_u32(const uint32_t* p) {
  return __hip_atomic_load(p, __ATOMIC_RELAXED, __HIP_MEMORY_SCOPE_AGENT);
}
__device__ __forceinline__ void st_dev_u32(uint32_t* p, uint32_t v) {
  __hip_atomic_store(p, v, __ATOMIC_RELAXED, __HIP_MEMORY_SCOPE_AGENT);
}

// Conservative bits-threshold from prune max m: all j with g_j > m must pass
// (bits>>9) >= k. u(bits) = (bits>>9)*2^-23 exactly; 1e-5 slack >> expf ulps.
__device__ __forceinline__ uint32_t prune_k(float m) {
  if (m == -INFINITY) return 0u;
  float t = expf(-expf(-m)) - 1e-5f;
  if (!(t > 0.0f)) return 0u;
  uint32_t k = (uint32_t)ceilf(t * 8388608.0f);
  return k > 8388607u ? 8388607u : k;
}

// Exact JAX-style evaluation of one accepted candidate.
__device__ __forceinline__ void full_eval(uint32_t bits, int j,
    const int* __restrict__ ids, const int* __restrict__ geto,
    const float* __restrict__ probs, int D,
    float& m, int& ix, float& pr, uint32_t& k) {
  float u = __uint_as_float((bits >> 9) | 0x3f800000u) - 1.0f;
  u = fmaxf(u, 1.17549435e-38f);
  float g = -logf(-logf(u));
  int b = j / D;               // rare path: plain int div is fine
  int d = j - b * D;
  float lp = logf(probs[geto[ids[b] * D + d]]);
  float v = g + lp;
  if (v > m) { m = v; ix = j; }       // strict > keeps first index
  if (v > pr) { pr = v; k = prune_k(pr); }
}

// ---- K1: per-(sample-pair, chunk) pruned argmax partials ------------------
__global__ __launch_bounds__(256) void sample_kernel(
    const int* __restrict__ ids, const int* __restrict__ geto,
    const float* __restrict__ probs,
    uint32_t* pmaxb, uint32_t* pidx,
    int NC, int D, int chunk, int CH, int S) {
  const int tid = threadIdx.x;
  const int c = blockIdx.x;                  // chunk id
  const int sl = blockIdx.y;                 // low sample of pair (0..S/2-1)
  const int j0 = c * chunk;
  const int jend = min(j0 + chunk, NC);
  const uint32_t dc = (uint32_t)(S / 2) * (uint32_t)NC;   // "half" offset
  const uint32_t cbase = (uint32_t)sl * (uint32_t)NC;

  float m0 = -INFINITY, m1 = -INFINITY;      // tracked max (with index)
  int ix0 = INT_MAX, ix1 = INT_MAX;
  float pr0 = -INFINITY, pr1 = -INFINITY;    // prune max (>= tracked)
  uint32_t k0 = 0u, k1 = 0u;

  const int nit = (jend - j0 + 255) / 256;   // uniform across the block
  int it = 0;
  while (it < nit) {
    int itend = min(it + 32, nit);
    for (; it < itend; ++it) {
      int j = j0 + tid + (it << 8);
      uint32_t cc0 = cbase + (uint32_t)j;
      uint32_t o0, o1;
      tf2x32_k42(cc0, cc0 + dc, o0, o1);     // one call -> samples sl, sl+S/2
      bool valid = (j < jend);
      if (valid && (o0 >> 9) >= k0)
        full_eval(o0, j, ids, geto, probs, D, m0, ix0, pr0, k0);
      if (valid && (o1 >> 9) >= k1)
        full_eval(o1, j, ids, geto, probs, D, m1, ix1, pr1, k1);
    }
    // Wave-share prune maxes (all 64 lanes present: nit is uniform).
    float w0 = pr0, w1 = pr1;
    for (int off = 32; off > 0; off >>= 1) {
      w0 = fmaxf(w0, __shfl_xor(w0, off));
      w1 = fmaxf(w1, __shfl_xor(w1, off));
    }
    if (w0 > pr0) { pr0 = w0; k0 = prune_k(pr0); }
    if (w1 > pr1) { pr1 = w1; k1 = prune_k(pr1); }
  }

  __shared__ float sv[256];
  __shared__ int si[256];
  // reduce sample sl
  sv[tid] = m0; si[tid] = ix0;
  __syncthreads();
  for (int w = 128; w > 0; w >>= 1) {
    if (tid < w) {
      float v2 = sv[tid + w]; int i2 = si[tid + w];
      if (v2 > sv[tid] || (v2 == sv[tid] && i2 < si[tid])) { sv[tid] = v2; si[tid] = i2; }
    }
    __syncthreads();
  }
  if (tid == 0) {
    st_dev_u32(&pmaxb[sl * CH + c], __float_as_uint(sv[0]));
    st_dev_u32(&pidx[sl * CH + c], (uint32_t)si[0]);
  }
  __syncthreads();
  // reduce sample sl + S/2
  sv[tid] = m1; si[tid] = ix1;
  __syncthreads();
  for (int w = 128; w > 0; w >>= 1) {
    if (tid < w) {
      float v2 = sv[tid + w]; int i2 = si[tid + w];
      if (v2 > sv[tid] || (v2 == sv[tid] && i2 < si[tid])) { sv[tid] = v2; si[tid] = i2; }
    }
    __syncthreads();
  }
  if (tid == 0) {
    st_dev_u32(&pmaxb[(sl + S / 2) * CH + c], __float_as_uint(sv[0]));
    st_dev_u32(&pidx[(sl + S / 2) * CH + c], (uint32_t)si[0]);
  }
}

// ---- K1b: final per-sample reduce + clip ----------------------------------
__global__ void reduce_kernel(const uint32_t* __restrict__ pmaxb,
                              const uint32_t* __restrict__ pidx,
                              uint32_t* __restrict__ ridx, int CH, int D) {
  const int s = blockIdx.x;
  const int t = threadIdx.x;   // 64 threads
  __shared__ float sv[64];
  __shared__ int si[64];
  float v = -INFINITY; int ix = INT_MAX;
  if (t < CH) {
    v = __uint_as_float(ld_dev_u32(&pmaxb[s * CH + t]));
    ix = (int)ld_dev_u32(&pidx[s * CH + t]);
  }
  sv[t] = v; si[t] = ix;
  __syncthreads();
  for (int w = 32; w > 0; w >>= 1) {
    if (t < w) {
      float v2 = sv[t + w]; int i2 = si[t + w];
      if (v2 > sv[t] || (v2 == sv[t] && i2 < si[t])) { sv[t] = v2; si[t] = i2; }
    }
    __syncthreads();
  }
  if (t == 0) {
    int r = si[0];
    r = r < 0 ? 0 : (r > D - 1 ? D - 1 : r);   // take(..., mode='clip')
    st_dev_u32(&ridx[s], (uint32_t)r);
  }
}

// ---- K2: gather outputs ----------------------------------------------------
__global__ __launch_bounds__(256) void gather_kernel(
    const int* __restrict__ ids, const int* __restrict__ adj,
    const int* __restrict__ geto, const uint32_t* __restrict__ ridx,
    int* __restrict__ out, int B, int D, int ns) {
  __shared__ int sr[64];
  if (threadIdx.x < ns) {
    int r = (int)ld_dev_u32(&ridx[threadIdx.x]);
    r = r < 0 ? 0 : (r > D - 1 ? D - 1 : r);   // defensive clamp
    sr[threadIdx.x] = r;
  }
  __syncthreads();
  int t = blockIdx.x * blockDim.x + threadIdx.x;
  int total = B * ns;
  if (t >= total) return;
  int b = t / ns;
  int s = t - b * ns;
  int r = sr[s];
  int row = ids[b];
  out[t] = adj[row * D + r];            // weighted_adj[:, :ns]
  out[total + t] = geto[row * D + r];   // weighted_geto[:, :ns]
}

// ---------------------------------------------------------------------------
extern "C" void kernel_launch(void* const* d_in, const int* in_sizes, int n_in,
                              void* d_out, int out_size, void* d_ws, size_t ws_size,
                              hipStream_t stream) {
  const int* ids = (const int*)d_in[0];
  const int* adj = (const int*)d_in[2];
  const int* geto = (const int*)d_in[3];
  const float* probs = (const float*)d_in[4];
  int* out = (int*)d_out;

  const int B = in_sizes[0];            // 100000
  const int D = in_sizes[2] / B;        // 64
  const int NC = B * D;                 // 6.4M categories
  const int S = D;                      // 64 samples (RESAMPLING_RATE = 0)
  const int ns = out_size / (2 * B);    // 25
  const int CH = 64;                    // chunks per sample
  const int chunk = (NC + CH - 1) / CH; // 100000

  // ws layout: [pmaxb: S*CH u32][pidx: S*CH u32][ridx: S u32]  (~33 KB)
  uint32_t* pmaxb = (uint32_t*)d_ws;
  uint32_t* pidx = pmaxb + (size_t)S * CH;
  uint32_t* ridx = pidx + (size_t)S * CH;

  dim3 gridB(CH, S / 2);
  sample_kernel<<<gridB, 256, 0, stream>>>(ids, geto, probs, pmaxb, pidx,
                                           NC, D, chunk, CH, S);
  reduce_kernel<<<S, 64, 0, stream>>>(pmaxb, pidx, ridx, CH, D);
  int total = B * ns;
  gather_kernel<<<(total + 255) / 256, 256, 0, stream>>>(
      ids, adj, geto, ridx, out, B, D, ns);
}

// Round 3
// 394.319 us; speedup vs baseline: 1.5777x; 1.5777x over previous
//
#include <hip/hip_runtime.h>
#include <stdint.h>
#include <limits.h>

// ---------------------------------------------------------------------------
// GeToInformedNeighborSampler — round 3.
//
// Only samples s < ns (=25) are consumed by the output, so only those argmaxes
// are computed (the Threefry pair partner of s<25 is s+32, never used).
//
// Exact pruning: lp<0 always, so beating running max m requires g_j > m, i.e.
// bits >= kb(m) (raw-domain compare, 1e-5 u-slack covers all float error —
// validated exactly in round 2). A seed kernel computes max(g+lp) over the
// first 65536 elements per sample (a valid lower bound), so the main loop's
// accept rate is ~4e-5 from the first iteration: no warm-up, no wave-sharing.
//
// All cross-kernel ws handoffs use AGENT-scope atomics (XCD-coherence, G16) —
// this fixed the round-1 graph-replay divergence.
// ---------------------------------------------------------------------------

#define DEVI __device__ __forceinline__

DEVI uint32_t rotl32(uint32_t x, int n) { return (x << n) | (x >> (32 - n)); }

// threefry2x32-20, key (0,42). Returns o0 only (o1 chain dead — last round's
// x1 rot/xor and final x1 injection are dropped).
DEVI uint32_t tf_o0(uint32_t c0, uint32_t c1) {
  const uint32_t K1 = 42u;
  const uint32_t K2 = 0x1BD11BDAu ^ K1;  // K0 = 0
  uint32_t x0 = c0;                      // + K0
  uint32_t x1 = c1 + K1;
#define TFR(r) x0 += x1; x1 = rotl32(x1, (r)); x1 ^= x0;
  TFR(13) TFR(15) TFR(26) TFR(6)
  x0 += K1; x1 += K2 + 1u;
  TFR(17) TFR(29) TFR(16) TFR(24)
  x0 += K2; x1 += 2u;                    // + K0 + 2
  TFR(13) TFR(15) TFR(26) TFR(6)
  /* x0 += K0 */ x1 += K1 + 3u;
  TFR(17) TFR(29) TFR(16) TFR(24)
  x0 += K1; x1 += K2 + 4u;
  TFR(13) TFR(15) TFR(26)
  x0 += x1;                              // round 20: only the add feeds o0
  x0 += K2;                              // final injection for o0
#undef TFR
  return x0;
}

// Device-scope coherence-point load/store (safe across kernels/XCDs).
DEVI uint32_t ld_dev_u32(const uint32_t* p) {
  return __hip_atomic_load(p, __ATOMIC_RELAXED, __HIP_MEMORY_SCOPE_AGENT);
}
DEVI void st_dev_u32(uint32_t* p, uint32_t v) {
  __hip_atomic_store(p, v, __ATOMIC_RELAXED, __HIP_MEMORY_SCOPE_AGENT);
}

// Raw-bits prune threshold: accept bits iff bits >= kb. kb = k<<9 with
// k = ceil((exp(-exp(-m)) - 1e-5) * 2^23); slack validated in round 2.
DEVI uint32_t prune_kb(float m) {
  float t = expf(-expf(-m)) - 1e-5f;
  if (!(t > 0.0f)) return 0u;
  uint32_t k = (uint32_t)ceilf(t * 8388608.0f);
  if (k > 8388607u) k = 8388607u;
  return k << 9;
}

// Exact JAX gumbel+logit evaluation of one accepted candidate (cold path).
DEVI void eval_one(uint32_t bits, uint32_t j,
                   const int* __restrict__ ids, const int* __restrict__ geto,
                   const float* __restrict__ probs, int D, int dlog,
                   float& m, int& ix, uint32_t& kb) {
  float u = __uint_as_float((bits >> 9) | 0x3f800000u) - 1.0f;
  u = fmaxf(u, 1.17549435e-38f);
  float g = -logf(-logf(u));
  uint32_t b, d;
  if (dlog >= 0) { b = j >> dlog; d = j & (uint32_t)(D - 1); }
  else { b = j / (uint32_t)D; d = j - b * (uint32_t)D; }
  float lp = logf(probs[geto[(uint32_t)ids[b] * (uint32_t)D + d]]);
  float v = g + lp;
  // first-index tie-break matters because m may start at the seed value
  if (v > m) { m = v; ix = (int)j; kb = prune_kb(v); }
  else if (v == m && (int)j < ix) { ix = (int)j; }
}

// ---- K0: seed — max(g+lp) over first SEEDB*SEEDE*256 elements per sample --
__global__ __launch_bounds__(256) void seed_kernel(
    const int* __restrict__ ids, const int* __restrict__ geto,
    const float* __restrict__ probs, uint32_t* __restrict__ seedp,
    int NC, int D, int dlog, uint32_t dc, int SEEDE) {
  const int c = blockIdx.x, s = blockIdx.y;
  const uint32_t sbase = (uint32_t)s * (uint32_t)NC;
  uint32_t j = (uint32_t)c * (uint32_t)(SEEDE * 256) + threadIdx.x;
  float m = -INFINITY;
  for (int k = 0; k < SEEDE; ++k) {
    uint32_t jj = j + (uint32_t)(k * 256);
    uint32_t cc = sbase + jj;
    uint32_t bits = tf_o0(cc, cc + dc);
    float u = __uint_as_float((bits >> 9) | 0x3f800000u) - 1.0f;
    u = fmaxf(u, 1.17549435e-38f);
    float g = -logf(-logf(u));
    uint32_t b, d;
    if (dlog >= 0) { b = jj >> dlog; d = jj & (uint32_t)(D - 1); }
    else { b = jj / (uint32_t)D; d = jj - b * (uint32_t)D; }
    float lp = logf(probs[geto[(uint32_t)ids[b] * (uint32_t)D + d]]);
    m = fmaxf(m, g + lp);
  }
  __shared__ float sv[256];
  sv[threadIdx.x] = m;
  __syncthreads();
  for (int w = 128; w > 0; w >>= 1) {
    if (threadIdx.x < w) sv[threadIdx.x] = fmaxf(sv[threadIdx.x], sv[threadIdx.x + w]);
    __syncthreads();
  }
  if (threadIdx.x == 0)
    st_dev_u32(&seedp[s * gridDim.x + c], __float_as_uint(sv[0]));
}

// ---- K1: pruned argmax over one chunk of one sample -----------------------
template <bool GUARD>
__global__ __launch_bounds__(256) void sample_kernel(
    const int* __restrict__ ids, const int* __restrict__ geto,
    const float* __restrict__ probs, const uint32_t* __restrict__ seedp,
    uint32_t* __restrict__ pmax, uint32_t* __restrict__ pidx,
    int NC, int D, int dlog, int len, int CH, int SEEDB, uint32_t dc) {
  const int tid = threadIdx.x;
  const int c = blockIdx.x, s = blockIdx.y;

  float m = -INFINITY;
  for (int q = 0; q < SEEDB; ++q)
    m = fmaxf(m, __uint_as_float(ld_dev_u32(&seedp[s * SEEDB + q])));
  int ix = INT_MAX;
  uint32_t kb = prune_kb(m);

  const uint32_t sbase = (uint32_t)s * (uint32_t)NC;
  const int j0 = c * len;
  const uint32_t jend = GUARD ? (uint32_t)min(j0 + len, NC) : 0u;
  uint32_t cc = sbase + (uint32_t)j0 + (uint32_t)tid;
  const int iters = (len + 1023) >> 10;

#pragma clang loop unroll(disable)
  for (int it = 0; it < iters; ++it) {
    uint32_t c0 = cc, c1 = cc + 256u, c2 = cc + 512u, c3 = cc + 768u;
    uint32_t a0 = tf_o0(c0, c0 + dc);
    uint32_t a1 = tf_o0(c1, c1 + dc);
    uint32_t a2 = tf_o0(c2, c2 + dc);
    uint32_t a3 = tf_o0(c3, c3 + dc);
    int hit = (a0 >= kb) | (a1 >= kb) | (a2 >= kb) | (a3 >= kb);
    if (__builtin_expect(hit, 0)) {
      uint32_t j = cc - sbase;
      if ((a0 >= kb) && (!GUARD || j < jend))
        eval_one(a0, j, ids, geto, probs, D, dlog, m, ix, kb);
      if ((a1 >= kb) && (!GUARD || j + 256u < jend))
        eval_one(a1, j + 256u, ids, geto, probs, D, dlog, m, ix, kb);
      if ((a2 >= kb) && (!GUARD || j + 512u < jend))
        eval_one(a2, j + 512u, ids, geto, probs, D, dlog, m, ix, kb);
      if ((a3 >= kb) && (!GUARD || j + 768u < jend))
        eval_one(a3, j + 768u, ids, geto, probs, D, dlog, m, ix, kb);
    }
    cc += 1024u;
  }

  __shared__ float sv[256];
  __shared__ int si[256];
  sv[tid] = m; si[tid] = ix;
  __syncthreads();
  for (int w = 128; w > 0; w >>= 1) {
    if (tid < w) {
      float v2 = sv[tid + w]; int i2 = si[tid + w];
      if (v2 > sv[tid] || (v2 == sv[tid] && i2 < si[tid])) { sv[tid] = v2; si[tid] = i2; }
    }
    __syncthreads();
  }
  if (tid == 0) {
    st_dev_u32(&pmax[s * CH + c], __float_as_uint(sv[0]));
    st_dev_u32(&pidx[s * CH + c], (uint32_t)si[0]);
  }
}

// ---- K2: final per-sample reduce + clip -----------------------------------
__global__ void reduce_kernel(const uint32_t* __restrict__ pmax,
                              const uint32_t* __restrict__ pidx,
                              uint32_t* __restrict__ ridx, int CH, int D) {
  const int s = blockIdx.x;
  const int t = threadIdx.x;  // 256 threads
  __shared__ float sv[256];
  __shared__ int si[256];
  float v = -INFINITY; int ix = INT_MAX;
  if (t < CH) {
    v = __uint_as_float(ld_dev_u32(&pmax[s * CH + t]));
    ix = (int)ld_dev_u32(&pidx[s * CH + t]);
  }
  sv[t] = v; si[t] = ix;
  __syncthreads();
  for (int w = 128; w > 0; w >>= 1) {
    if (t < w) {
      float v2 = sv[t + w]; int i2 = si[t + w];
      if (v2 > sv[t] || (v2 == sv[t] && i2 < si[t])) { sv[t] = v2; si[t] = i2; }
    }
    __syncthreads();
  }
  if (t == 0) {
    int r = si[0];
    r = r < 0 ? 0 : (r > D - 1 ? D - 1 : r);  // take(..., mode='clip')
    st_dev_u32(&ridx[s], (uint32_t)r);
  }
}

// ---- K3: gather outputs ----------------------------------------------------
__global__ __launch_bounds__(256) void gather_kernel(
    const int* __restrict__ ids, const int* __restrict__ adj,
    const int* __restrict__ geto, const uint32_t* __restrict__ ridx,
    int* __restrict__ out, int B, int D, int ns) {
  __shared__ int sr[64];
  if (threadIdx.x < ns) {
    int r = (int)ld_dev_u32(&ridx[threadIdx.x]);
    r = r < 0 ? 0 : (r > D - 1 ? D - 1 : r);  // defensive clamp
    sr[threadIdx.x] = r;
  }
  __syncthreads();
  int t = blockIdx.x * blockDim.x + threadIdx.x;
  int total = B * ns;
  if (t >= total) return;
  int b = t / ns;
  int s = t - b * ns;
  int r = sr[s];
  int row = ids[b];
  out[t] = adj[row * D + r];            // weighted_adj[:, :ns]
  out[total + t] = geto[row * D + r];   // weighted_geto[:, :ns]
}

// ---------------------------------------------------------------------------
extern "C" void kernel_launch(void* const* d_in, const int* in_sizes, int n_in,
                              void* d_out, int out_size, void* d_ws, size_t ws_size,
                              hipStream_t stream) {
  const int* ids = (const int*)d_in[0];
  const int* adj = (const int*)d_in[2];
  const int* geto = (const int*)d_in[3];
  const float* probs = (const float*)d_in[4];
  int* out = (int*)d_out;

  const int B = in_sizes[0];             // 100000
  const int D = in_sizes[2] / B;         // 64
  const int NC = B * D;                  // 6.4M categories
  const int S = D;                       // 64 total samples (RESAMPLING_RATE=0)
  const int ns = out_size / (2 * B);     // 25 — only these are consumed
  const uint32_t dc = (uint32_t)(S / 2) * (uint32_t)NC;  // classic-mode half
  const int dlog = ((D & (D - 1)) == 0) ? __builtin_ctz(D) : -1;

  // Seed geometry: SEEDB blocks x 256 threads x SEEDE elements per sample.
  int SEEDB = 16, SEEDE = 16;
  while (SEEDB > 1 && SEEDB * SEEDE * 256 > NC) SEEDB >>= 1;   // generic guard

  // Chunk count: prefer exact 1024-multiples of NC (no bounds checks).
  const int cands[8] = {250, 125, 50, 25, 10, 5, 2, 1};
  int CH = -1;
  for (int i = 0; i < 8; ++i) {
    int ch = cands[i];
    if (NC % (ch * 1024) != 0) continue;
    size_t need = (size_t)ns * ch * 8 + (size_t)ns * SEEDB * 4 + 256;
    if (need <= ws_size) { CH = ch; break; }
  }
  bool guard = false;
  int len;
  if (CH < 0) { CH = 64; len = (((NC + CH - 1) / CH) + 1023) & ~1023; guard = true; }
  else        { len = NC / CH; }

  // ws layout: [pmax ns*CH][pidx ns*CH][seedp ns*SEEDB][ridx 64]
  uint32_t* pmax = (uint32_t*)d_ws;
  uint32_t* pidx = pmax + (size_t)ns * CH;
  uint32_t* seedp = pidx + (size_t)ns * CH;
  uint32_t* ridx = seedp + (size_t)ns * SEEDB;

  seed_kernel<<<dim3(SEEDB, ns), 256, 0, stream>>>(ids, geto, probs, seedp,
                                                   NC, D, dlog, dc, SEEDE);
  if (guard)
    sample_kernel<true><<<dim3(CH, ns), 256, 0, stream>>>(
        ids, geto, probs, seedp, pmax, pidx, NC, D, dlog, len, CH, SEEDB, dc);
  else
    sample_kernel<false><<<dim3(CH, ns), 256, 0, stream>>>(
        ids, geto, probs, seedp, pmax, pidx, NC, D, dlog, len, CH, SEEDB, dc);
  reduce_kernel<<<ns, 256, 0, stream>>>(pmax, pidx, ridx, CH, D);

  int total = B * ns;
  gather_kernel<<<(total + 255) / 256, 256, 0, stream>>>(
      ids, adj, geto, ridx, out, B, D, ns);
}

// Round 4
// 305.374 us; speedup vs baseline: 2.0372x; 1.2913x over previous
//
#include <hip/hip_runtime.h>
#include <stdint.h>
#include <limits.h>

// ---------------------------------------------------------------------------
// GeToInformedNeighborSampler — round 4 (hot-loop micro-opt).
//
// Semantics identical to round 3 (passed, absmax 0): only samples s < ns are
// computed; exact raw-bits pruning (bits >= kb ⟺ (bits>>9) >= k, exact);
// seed kernel gives a valid lower bound so main-loop accept rate ~1.5e-5;
// AGENT-scope atomics for every cross-kernel ws handoff (G16).
//
// This round: 8 hash chains/iter, pre-folded (+dc+42) literal, umax-tree hit
// test, launch_bounds(256,4). Pure codegen experiment, no semantic change.
// ---------------------------------------------------------------------------

#define DEVI __device__ __forceinline__

DEVI uint32_t rotl32(uint32_t x, int n) { return (x << n) | (x >> (32 - n)); }

// threefry2x32-20, key (0,42), o0 only. x1 must already include +K1 (=42).
DEVI uint32_t tf_o0p(uint32_t x0, uint32_t x1) {
  const uint32_t K1 = 42u;
  const uint32_t K2 = 0x1BD11BDAu ^ K1;  // K0 = 0
#define TFR(r) x0 += x1; x1 = rotl32(x1, (r)); x1 ^= x0;
  TFR(13) TFR(15) TFR(26) TFR(6)
  x0 += K1; x1 += K2 + 1u;
  TFR(17) TFR(29) TFR(16) TFR(24)
  x0 += K2; x1 += 2u;                    // + K0 + 2
  TFR(13) TFR(15) TFR(26) TFR(6)
  /* x0 += K0 */ x1 += K1 + 3u;
  TFR(17) TFR(29) TFR(16) TFR(24)
  x0 += K1; x1 += K2 + 4u;
  TFR(13) TFR(15) TFR(26)
  x0 += x1;                              // round 20: only the add feeds o0
  x0 += K2;                              // final injection for o0
#undef TFR
  return x0;
}

// Device-scope coherence-point load/store (safe across kernels/XCDs).
DEVI uint32_t ld_dev_u32(const uint32_t* p) {
  return __hip_atomic_load(p, __ATOMIC_RELAXED, __HIP_MEMORY_SCOPE_AGENT);
}
DEVI void st_dev_u32(uint32_t* p, uint32_t v) {
  __hip_atomic_store(p, v, __ATOMIC_RELAXED, __HIP_MEMORY_SCOPE_AGENT);
}

// Raw-bits prune threshold: accept bits iff bits >= kb (kb = k<<9), with
// k = ceil((exp(-exp(-m)) - 1e-5) * 2^23). Exactness validated rounds 2-3.
DEVI uint32_t prune_kb(float m) {
  float t = expf(-expf(-m)) - 1e-5f;
  if (!(t > 0.0f)) return 0u;
  uint32_t k = (uint32_t)ceilf(t * 8388608.0f);
  if (k > 8388607u) k = 8388607u;
  return k << 9;
}

// Exact JAX gumbel+logit evaluation of one accepted candidate (cold path).
DEVI void eval_one(uint32_t bits, uint32_t j,
                   const int* __restrict__ ids, const int* __restrict__ geto,
                   const float* __restrict__ probs, int D, int dlog,
                   float& m, int& ix, uint32_t& kb) {
  float u = __uint_as_float((bits >> 9) | 0x3f800000u) - 1.0f;
  u = fmaxf(u, 1.17549435e-38f);
  float g = -logf(-logf(u));
  uint32_t b, d;
  if (dlog >= 0) { b = j >> dlog; d = j & (uint32_t)(D - 1); }
  else { b = j / (uint32_t)D; d = j - b * (uint32_t)D; }
  float lp = logf(probs[geto[(uint32_t)ids[b] * (uint32_t)D + d]]);
  float v = g + lp;
  if (v > m) { m = v; ix = (int)j; kb = prune_kb(v); }
  else if (v == m && (int)j < ix) { ix = (int)j; }  // first-index tie-break
}

// ---- K0: seed — max(g+lp) over first SEEDB*SEEDE*256 elements per sample --
__global__ __launch_bounds__(256) void seed_kernel(
    const int* __restrict__ ids, const int* __restrict__ geto,
    const float* __restrict__ probs, uint32_t* __restrict__ seedp,
    int NC, int D, int dlog, uint32_t dcK, int SEEDE) {
  const int c = blockIdx.x, s = blockIdx.y;
  const uint32_t sbase = (uint32_t)s * (uint32_t)NC;
  uint32_t j = (uint32_t)c * (uint32_t)(SEEDE * 256) + threadIdx.x;
  float m = -INFINITY;
  for (int k = 0; k < SEEDE; ++k) {
    uint32_t jj = j + (uint32_t)(k * 256);
    uint32_t cc = sbase + jj;
    uint32_t bits = tf_o0p(cc, cc + dcK);
    float u = __uint_as_float((bits >> 9) | 0x3f800000u) - 1.0f;
    u = fmaxf(u, 1.17549435e-38f);
    float g = -logf(-logf(u));
    uint32_t b, d;
    if (dlog >= 0) { b = jj >> dlog; d = jj & (uint32_t)(D - 1); }
    else { b = jj / (uint32_t)D; d = jj - b * (uint32_t)D; }
    float lp = logf(probs[geto[(uint32_t)ids[b] * (uint32_t)D + d]]);
    m = fmaxf(m, g + lp);
  }
  __shared__ float sv[256];
  sv[threadIdx.x] = m;
  __syncthreads();
  for (int w = 128; w > 0; w >>= 1) {
    if (threadIdx.x < w) sv[threadIdx.x] = fmaxf(sv[threadIdx.x], sv[threadIdx.x + w]);
    __syncthreads();
  }
  if (threadIdx.x == 0)
    st_dev_u32(&seedp[s * gridDim.x + c], __float_as_uint(sv[0]));
}

// ---- K1: pruned argmax over one chunk of one sample -----------------------
template <bool GUARD>
__global__ __launch_bounds__(256, 4) void sample_kernel(
    const int* __restrict__ ids, const int* __restrict__ geto,
    const float* __restrict__ probs, const uint32_t* __restrict__ seedp,
    uint32_t* __restrict__ pmax, uint32_t* __restrict__ pidx,
    int NC, int D, int dlog, int len, int CH, int SEEDB, uint32_t dcK) {
  const int tid = threadIdx.x;
  const int c = blockIdx.x, s = blockIdx.y;

  float m = -INFINITY;
  for (int q = 0; q < SEEDB; ++q)
    m = fmaxf(m, __uint_as_float(ld_dev_u32(&seedp[s * SEEDB + q])));
  int ix = INT_MAX;
  uint32_t kb = prune_kb(m);

  const uint32_t sbase = (uint32_t)s * (uint32_t)NC;
  const int j0 = c * len;
  const uint32_t jend = GUARD ? (uint32_t)min(j0 + len, NC) : 0u;
  uint32_t cc = sbase + (uint32_t)j0 + (uint32_t)tid;
  const int iters = (len + 2047) >> 11;

#pragma clang loop unroll(disable)
  for (int it = 0; it < iters; ++it) {
    uint32_t a[8];
#pragma unroll
    for (int i = 0; i < 8; ++i) {
      uint32_t c0 = cc + (uint32_t)(i * 256);
      a[i] = tf_o0p(c0, c0 + dcK);
    }
    // hit test: nested umax (fuses to v_max3_u32) + one compare
    uint32_t mx01 = a[0] > a[1] ? a[0] : a[1];
    uint32_t mx = mx01 > a[2] ? mx01 : a[2];
    uint32_t mx34 = a[3] > a[4] ? a[3] : a[4];
    uint32_t mxb = mx34 > a[5] ? mx34 : a[5];
    uint32_t mx67 = a[6] > a[7] ? a[6] : a[7];
    uint32_t mall = mx > mxb ? mx : mxb;
    mall = mall > mx67 ? mall : mx67;
    if (__builtin_expect(mall >= kb, 0)) {
      uint32_t j = cc - sbase;
#pragma unroll
      for (int i = 0; i < 8; ++i) {
        uint32_t ji = j + (uint32_t)(i * 256);
        if ((a[i] >= kb) && (!GUARD || ji < jend))
          eval_one(a[i], ji, ids, geto, probs, D, dlog, m, ix, kb);
      }
    }
    cc += 2048u;
  }

  __shared__ float sv[256];
  __shared__ int si[256];
  sv[tid] = m; si[tid] = ix;
  __syncthreads();
  for (int w = 128; w > 0; w >>= 1) {
    if (tid < w) {
      float v2 = sv[tid + w]; int i2 = si[tid + w];
      if (v2 > sv[tid] || (v2 == sv[tid] && i2 < si[tid])) { sv[tid] = v2; si[tid] = i2; }
    }
    __syncthreads();
  }
  if (tid == 0) {
    st_dev_u32(&pmax[s * CH + c], __float_as_uint(sv[0]));
    st_dev_u32(&pidx[s * CH + c], (uint32_t)si[0]);
  }
}

// ---- K2: final per-sample reduce + clip -----------------------------------
__global__ void reduce_kernel(const uint32_t* __restrict__ pmax,
                              const uint32_t* __restrict__ pidx,
                              uint32_t* __restrict__ ridx, int CH, int D) {
  const int s = blockIdx.x;
  const int t = threadIdx.x;  // 256 threads
  __shared__ float sv[256];
  __shared__ int si[256];
  float v = -INFINITY; int ix = INT_MAX;
  for (int q = t; q < CH; q += 256) {
    float v2 = __uint_as_float(ld_dev_u32(&pmax[s * CH + q]));
    int i2 = (int)ld_dev_u32(&pidx[s * CH + q]);
    if (v2 > v || (v2 == v && i2 < ix)) { v = v2; ix = i2; }
  }
  sv[t] = v; si[t] = ix;
  __syncthreads();
  for (int w = 128; w > 0; w >>= 1) {
    if (t < w) {
      float v2 = sv[t + w]; int i2 = si[t + w];
      if (v2 > sv[t] || (v2 == sv[t] && i2 < si[t])) { sv[t] = v2; si[t] = i2; }
    }
    __syncthreads();
  }
  if (t == 0) {
    int r = si[0];
    r = r < 0 ? 0 : (r > D - 1 ? D - 1 : r);  // take(..., mode='clip')
    st_dev_u32(&ridx[s], (uint32_t)r);
  }
}

// ---- K3: gather outputs ----------------------------------------------------
__global__ __launch_bounds__(256) void gather_kernel(
    const int* __restrict__ ids, const int* __restrict__ adj,
    const int* __restrict__ geto, const uint32_t* __restrict__ ridx,
    int* __restrict__ out, int B, int D, int ns) {
  __shared__ int sr[64];
  if (threadIdx.x < ns) {
    int r = (int)ld_dev_u32(&ridx[threadIdx.x]);
    r = r < 0 ? 0 : (r > D - 1 ? D - 1 : r);  // defensive clamp
    sr[threadIdx.x] = r;
  }
  __syncthreads();
  int t = blockIdx.x * blockDim.x + threadIdx.x;
  int total = B * ns;
  if (t >= total) return;
  int b = t / ns;
  int s = t - b * ns;
  int r = sr[s];
  int row = ids[b];
  out[t] = adj[row * D + r];            // weighted_adj[:, :ns]
  out[total + t] = geto[row * D + r];   // weighted_geto[:, :ns]
}

// ---------------------------------------------------------------------------
extern "C" void kernel_launch(void* const* d_in, const int* in_sizes, int n_in,
                              void* d_out, int out_size, void* d_ws, size_t ws_size,
                              hipStream_t stream) {
  const int* ids = (const int*)d_in[0];
  const int* adj = (const int*)d_in[2];
  const int* geto = (const int*)d_in[3];
  const float* probs = (const float*)d_in[4];
  int* out = (int*)d_out;

  const int B = in_sizes[0];             // 100000
  const int D = in_sizes[2] / B;         // 64
  const int NC = B * D;                  // 6.4M categories
  const int S = D;                       // 64 total samples (RESAMPLING_RATE=0)
  const int ns = out_size / (2 * B);     // 25 — only these are consumed
  const uint32_t dc = (uint32_t)(S / 2) * (uint32_t)NC;  // classic-mode half
  const uint32_t dcK = dc + 42u;         // fold +K1 into the counter offset
  const int dlog = ((D & (D - 1)) == 0) ? __builtin_ctz(D) : -1;

  // Seed geometry: SEEDB blocks x 256 threads x SEEDE elements per sample.
  int SEEDB = 16, SEEDE = 16;
  while (SEEDB > 1 && SEEDB * SEEDE * 256 > NC) SEEDB >>= 1;

  // Chunk count: prefer exact 2048-multiples of NC (no bounds checks).
  const int cands[8] = {125, 250, 64, 50, 25, 10, 5, 1};
  int CH = -1;
  for (int i = 0; i < 8; ++i) {
    int ch = cands[i];
    if (NC % (ch * 2048) != 0) continue;
    size_t need = (size_t)ns * ch * 8 + (size_t)ns * SEEDB * 4 + 256;
    if (need <= ws_size) { CH = ch; break; }
  }
  bool guard = false;
  int len;
  if (CH < 0) { CH = 64; len = (((NC + CH - 1) / CH) + 2047) & ~2047; guard = true; }
  else        { len = NC / CH; }

  // ws layout: [pmax ns*CH][pidx ns*CH][seedp ns*SEEDB][ridx 64]
  uint32_t* pmax = (uint32_t*)d_ws;
  uint32_t* pidx = pmax + (size_t)ns * CH;
  uint32_t* seedp = pidx + (size_t)ns * CH;
  uint32_t* ridx = seedp + (size_t)ns * SEEDB;

  seed_kernel<<<dim3(SEEDB, ns), 256, 0, stream>>>(ids, geto, probs, seedp,
                                                   NC, D, dlog, dcK, SEEDE);
  if (guard)
    sample_kernel<true><<<dim3(CH, ns), 256, 0, stream>>>(
        ids, geto, probs, seedp, pmax, pidx, NC, D, dlog, len, CH, SEEDB, dcK);
  else
    sample_kernel<false><<<dim3(CH, ns), 256, 0, stream>>>(
        ids, geto, probs, seedp, pmax, pidx, NC, D, dlog, len, CH, SEEDB, dcK);
  reduce_kernel<<<ns, 256, 0, stream>>>(pmax, pidx, ridx, CH, D);

  int total = B * ns;
  gather_kernel<<<(total + 255) / 256, 256, 0, stream>>>(
      ids, adj, geto, ridx, out, B, D, ns);
}

// Round 5
// 101.735 us; speedup vs baseline: 6.1150x; 3.0017x over previous
//
#include <hip/hip_runtime.h>
#include <stdint.h>
#include <limits.h>

// ---------------------------------------------------------------------------
// GeToInformedNeighborSampler — round 5 (exact clip-aware early-exit).
//
// Reference: idx[s] = argmax_{j<NC} v_j,  v_j = gumbel(s*NC+j) + logp[j],
//            r[s] = clip(idx[s], 0, D-1);  outputs gather column r[s].
//
// Clip discards everything about idx[s] except (a) whether idx[s] < D and
// (b) its value in that case. Exactly:
//   A = max_{j<D} v_j, a = first argmax;   (D = 64 elements — trivial)
//   r = (exists j in [D,NC) with v_j > A) ? D-1 : a
// (strict >: a tie at j>=D still leaves the first attainer at a < D).
// The existence scan uses the raw-bits prune filter (lp<0 => v_j>A requires
// bits >= kb(A), conservative slack validated rounds 2-4) and EARLY-EXITS at
// the first witness: P(one draw beats the max of 64 prior) ~ 1/65, so the
// expected scan is ~one 2048-tile per sample. Worst case = full scan (still
// exact). Deterministic per input => graph-replay-safe.
//
// Evidence this matches the reference here: rounds 1 (partitionable RNG) and
// 2-4 (classic RNG) produce different gumbel fields yet BOTH passed with
// absmax 0 => every reference sample clips to D-1; out_npz size confirms.
//
// Cross-kernel ws handoff (ridx) uses AGENT-scope atomics (G16; fixed the
// round-1 graph-replay divergence).
// ---------------------------------------------------------------------------

#define DEVI __device__ __forceinline__

DEVI uint32_t rotl32(uint32_t x, int n) { return (x << n) | (x >> (32 - n)); }

// threefry2x32-20, key (0,42), o0 only. x1 must already include +K1 (=42).
DEVI uint32_t tf_o0p(uint32_t x0, uint32_t x1) {
  const uint32_t K1 = 42u;
  const uint32_t K2 = 0x1BD11BDAu ^ K1;  // K0 = 0
#define TFR(r) x0 += x1; x1 = rotl32(x1, (r)); x1 ^= x0;
  TFR(13) TFR(15) TFR(26) TFR(6)
  x0 += K1; x1 += K2 + 1u;
  TFR(17) TFR(29) TFR(16) TFR(24)
  x0 += K2; x1 += 2u;                    // + K0 + 2
  TFR(13) TFR(15) TFR(26) TFR(6)
  /* x0 += K0 */ x1 += K1 + 3u;
  TFR(17) TFR(29) TFR(16) TFR(24)
  x0 += K1; x1 += K2 + 4u;
  TFR(13) TFR(15) TFR(26)
  x0 += x1;                              // round 20: only the add feeds o0
  x0 += K2;                              // final injection for o0
#undef TFR
  return x0;
}

// Device-scope coherence-point load/store (safe across kernels/XCDs).
DEVI uint32_t ld_dev_u32(const uint32_t* p) {
  return __hip_atomic_load(p, __ATOMIC_RELAXED, __HIP_MEMORY_SCOPE_AGENT);
}
DEVI void st_dev_u32(uint32_t* p, uint32_t v) {
  __hip_atomic_store(p, v, __ATOMIC_RELAXED, __HIP_MEMORY_SCOPE_AGENT);
}

// Raw-bits prune threshold: all j with g_j > m satisfy bits >= kb(m).
// kb = ceil((exp(-exp(-m)) - 1e-5) * 2^23) << 9; slack validated rounds 2-4.
DEVI uint32_t prune_kb(float m) {
  float t = expf(-expf(-m)) - 1e-5f;
  if (!(t > 0.0f)) return 0u;
  uint32_t k = (uint32_t)ceilf(t * 8388608.0f);
  if (k > 8388607u) k = 8388607u;
  return k << 9;
}

// Exact JAX gumbel+logit value of element j of one sample.
DEVI float eval_v(uint32_t bits, uint32_t j,
                  const int* __restrict__ ids, const int* __restrict__ geto,
                  const float* __restrict__ probs, int D, int dlog) {
  float u = __uint_as_float((bits >> 9) | 0x3f800000u) - 1.0f;
  u = fmaxf(u, 1.17549435e-38f);
  float g = -logf(-logf(u));
  uint32_t b, d;
  if (dlog >= 0) { b = j >> dlog; d = j & (uint32_t)(D - 1); }
  else { b = j / (uint32_t)D; d = j - b * (uint32_t)D; }
  float lp = logf(probs[geto[(uint32_t)ids[b] * (uint32_t)D + d]]);
  return g + lp;
}

// ---- K1: per-sample decision (A over j<D, then early-exit witness scan) ---
__global__ __launch_bounds__(256) void decide_kernel(
    const int* __restrict__ ids, const int* __restrict__ geto,
    const float* __restrict__ probs, uint32_t* __restrict__ ridx,
    int NC, int D, int dlog, uint32_t dcK) {
  const int s = blockIdx.x;
  const int tid = threadIdx.x;
  const uint32_t sbase = (uint32_t)s * (uint32_t)NC;
  const uint32_t total = (uint32_t)NC;

  // Phase A: max + first-argmax over j in [0, D).
  float av = -INFINITY;
  int ai = INT_MAX;
  for (uint32_t j = (uint32_t)tid; j < (uint32_t)D; j += 256u) {
    uint32_t cc = sbase + j;
    float v = eval_v(tf_o0p(cc, cc + dcK), j, ids, geto, probs, D, dlog);
    if (v > av) { av = v; ai = (int)j; }   // ascending j: > keeps first
  }
  __shared__ float sv[256];
  __shared__ int si[256];
  sv[tid] = av; si[tid] = ai;
  __syncthreads();
  for (int w = 128; w > 0; w >>= 1) {
    if (tid < w) {
      float v2 = sv[tid + w]; int i2 = si[tid + w];
      if (v2 > sv[tid] || (v2 == sv[tid] && i2 < si[tid])) { sv[tid] = v2; si[tid] = i2; }
    }
    __syncthreads();
  }
  const float A = sv[0];
  const int a0 = si[0];
  const uint32_t kb = prune_kb(A);

  __shared__ int sflag;
  if (tid == 0) sflag = 0;
  __syncthreads();

  // Phase B: scan j in [D, NC) for a witness v_j > A; exit at first tile
  // containing one. Expected ~1 tile; worst case full scan (still exact).
  bool done = false;
  for (uint32_t base = (uint32_t)D; base < total; base += 2048u) {
    bool found = false;
#pragma unroll
    for (int i = 0; i < 8; ++i) {
      uint32_t j = base + (uint32_t)tid + (uint32_t)(i * 256);
      uint32_t cc = sbase + j;
      uint32_t bits = tf_o0p(cc, cc + dcK);
      if (bits >= kb && j < total) {
        if (eval_v(bits, j, ids, geto, probs, D, dlog) > A) found = true;
      }
    }
    if (found) sflag = 1;
    __syncthreads();            // writes of this tile visible
    done = (sflag != 0);        // uniform read
    __syncthreads();            // no thread re-writes before all have read
    if (done) break;
  }

  if (tid == 0) {
    int r = done ? (D - 1) : a0;
    r = r < 0 ? 0 : (r > D - 1 ? D - 1 : r);  // take(..., mode='clip')
    st_dev_u32(&ridx[s], (uint32_t)r);
  }
}

// ---- K2: gather outputs ----------------------------------------------------
__global__ __launch_bounds__(256) void gather_kernel(
    const int* __restrict__ ids, const int* __restrict__ adj,
    const int* __restrict__ geto, const uint32_t* __restrict__ ridx,
    int* __restrict__ out, int B, int D, int ns) {
  __shared__ int sr[64];
  if (threadIdx.x < ns) {
    int r = (int)ld_dev_u32(&ridx[threadIdx.x]);
    r = r < 0 ? 0 : (r > D - 1 ? D - 1 : r);  // defensive clamp
    sr[threadIdx.x] = r;
  }
  __syncthreads();
  int t = blockIdx.x * blockDim.x + threadIdx.x;
  int total = B * ns;
  if (t >= total) return;
  int b = t / ns;
  int s = t - b * ns;
  int r = sr[s];
  int row = ids[b];
  out[t] = adj[row * D + r];            // weighted_adj[:, :ns]
  out[total + t] = geto[row * D + r];   // weighted_geto[:, :ns]
}

// ---------------------------------------------------------------------------
extern "C" void kernel_launch(void* const* d_in, const int* in_sizes, int n_in,
                              void* d_out, int out_size, void* d_ws, size_t ws_size,
                              hipStream_t stream) {
  const int* ids = (const int*)d_in[0];
  const int* adj = (const int*)d_in[2];
  const int* geto = (const int*)d_in[3];
  const float* probs = (const float*)d_in[4];
  int* out = (int*)d_out;

  const int B = in_sizes[0];             // 100000
  const int D = in_sizes[2] / B;         // 64
  const int NC = B * D;                  // 6.4M categories
  const int S = D;                       // 64 total samples (RESAMPLING_RATE=0)
  const int ns = out_size / (2 * B);     // 25 — only these are consumed
  const uint32_t dc = (uint32_t)(S / 2) * (uint32_t)NC;  // classic-mode half
  const uint32_t dcK = dc + 42u;         // fold +K1 into the counter offset
  const int dlog = ((D & (D - 1)) == 0) ? __builtin_ctz(D) : -1;

  // ws layout: [ridx: 64 u32]
  uint32_t* ridx = (uint32_t*)d_ws;

  decide_kernel<<<ns, 256, 0, stream>>>(ids, geto, probs, ridx,
                                        NC, D, dlog, dcK);
  int total = B * ns;
  gather_kernel<<<(total + 255) / 256, 256, 0, stream>>>(
      ids, adj, geto, ridx, out, B, D, ns);
}